// Round 1
// baseline (592.911 us; speedup 1.0000x reference)
//
#include <hip/hip_runtime.h>
#include <hip/hip_bf16.h>
#include <cstdint>

#define B_DIM 4096
#define H_DIM 2048
#define I_DIM 2048
#define K_DIM 4096   // combined = H + I
#define N4    8192   // 4 * H

typedef unsigned int u32;
typedef unsigned short u16;
typedef __attribute__((ext_vector_type(4))) float floatx4;
typedef __attribute__((ext_vector_type(8))) short bf16x8;

__device__ static inline u16 f2bf(float f) {
    union { float f; u32 u; } v; v.f = f;
    u32 u = v.u;
    return (u16)((u + 0x7FFFu + ((u >> 16) & 1u)) >> 16);  // RNE
}
__device__ static inline float bf2f(u16 h) {
    union { u32 u; float f; } v; v.u = ((u32)h) << 16;
    return v.f;
}
__device__ static inline void gload16(const void* g, void* l) {
    __builtin_amdgcn_global_load_lds(
        (const __attribute__((address_space(1))) u32*)g,
        (__attribute__((address_space(3))) u32*)l, 16, 0, 0);
}

// ---------------------------------------------------------------------------
// Kernel 1a: combined = bf16(concat([h_prev, x_t], axis=1))  [4096][4096]
// ---------------------------------------------------------------------------
__global__ void convert_combined(const float* __restrict__ h_prev,
                                 const float* __restrict__ x_t,
                                 u16* __restrict__ comb) {
    int t = blockIdx.x * blockDim.x + threadIdx.x;   // one thread per 4 elems
    int base = t * 4;                                 // < 2^24, int ok
    int row = base >> 12;           // / 4096
    int col = base & 4095;
    const float* src = (col < H_DIM)
        ? (h_prev + row * H_DIM + col)
        : (x_t    + row * I_DIM + (col - H_DIM));
    float4 v = *(const float4*)src;
    ushort4 o = { f2bf(v.x), f2bf(v.y), f2bf(v.z), f2bf(v.w) };
    *(ushort4*)(comb + base) = o;
}

// ---------------------------------------------------------------------------
// Kernel 1b: Wb[8192][4096] = bf16(concat([W_f, W_i, W_c, W_o], axis=0))
// ---------------------------------------------------------------------------
__global__ void convert_w(const float* __restrict__ Wf, const float* __restrict__ Wi,
                          const float* __restrict__ Wc, const float* __restrict__ Wo,
                          u16* __restrict__ wb) {
    long long t = (long long)blockIdx.x * blockDim.x + threadIdx.x;
    long long base = t * 4;                           // up to 2^25
    int row = (int)(base >> 12);
    int col = (int)(base & 4095);
    int g = row >> 11, j = row & 2047;
    const float* W = (g == 0) ? Wf : (g == 1) ? Wi : (g == 2) ? Wc : Wo;
    float4 v = *(const float4*)(W + (long long)j * K_DIM + col);
    ushort4 o = { f2bf(v.x), f2bf(v.y), f2bf(v.z), f2bf(v.w) };
    *(ushort4*)(wb + base) = o;
}

// ---------------------------------------------------------------------------
// Kernel 2: gates[4096][8192] (bf16) = comb @ Wb^T
// m97 structure: 128x128 tile, BK=32, global_load_lds x16, mfma 16x16x32 bf16.
// 256 threads = 4 waves in 2x2; each wave 64x64 = 4x4 grid of 16x16 MFMAs.
// LDS tiles UNPADDED [128][32] (required by global_load_lds lane layout).
// ---------------------------------------------------------------------------
__global__ __launch_bounds__(256) void gemm_gates(const u16* __restrict__ A,
                                                  const u16* __restrict__ Bm,
                                                  u16* __restrict__ G) {
    __shared__ u16 lsA[128 * 32];
    __shared__ u16 lsB[128 * 32];

    const int tid  = threadIdx.x;
    const int lane = tid & 63;
    const int wave = tid >> 6;
    const int wm   = (wave & 1) * 64;
    const int wn   = (wave >> 1) * 64;
    const int quad = lane >> 4;      // 0..3
    const int r    = lane & 15;      // 0..15
    const int mb   = blockIdx.y * 128;   // batch tile
    const int nb   = blockIdx.x * 128;   // gate-col tile (over 8192)

    floatx4 acc[4][4];
#pragma unroll
    for (int i = 0; i < 4; i++)
#pragma unroll
        for (int j = 0; j < 4; j++)
            acc[i][j] = (floatx4){0.f, 0.f, 0.f, 0.f};

    for (int kt = 0; kt < K_DIM; kt += 32) {
        __syncthreads();
#pragma unroll
        for (int s = 0; s < 2; s++) {
            int c   = tid + s * 256;          // chunk 0..511, 16B each
            int row = c >> 2;                 // 0..127
            int ko  = (c & 3) * 8;            // bf16 elems
            gload16(A  + (mb + row) * K_DIM + kt + ko, (char*)lsA + c * 16);
            gload16(Bm + (nb + row) * K_DIM + kt + ko, (char*)lsB + c * 16);
        }
        __syncthreads();

        bf16x8 af[4], bfr[4];
#pragma unroll
        for (int i = 0; i < 4; i++)
            af[i] = *(const bf16x8*)&lsA[(wm + i * 16 + r) * 32 + quad * 8];
#pragma unroll
        for (int j = 0; j < 4; j++)
            bfr[j] = *(const bf16x8*)&lsB[(wn + j * 16 + r) * 32 + quad * 8];
#pragma unroll
        for (int i = 0; i < 4; i++)
#pragma unroll
            for (int j = 0; j < 4; j++)
                acc[i][j] = __builtin_amdgcn_mfma_f32_16x16x32_bf16(
                    af[i], bfr[j], acc[i][j], 0, 0, 0);
    }

    // C/D layout: col = lane&15, row = quad*4 + reg  [m89/m91-verified]
#pragma unroll
    for (int i = 0; i < 4; i++)
#pragma unroll
        for (int j = 0; j < 4; j++)
#pragma unroll
            for (int rg = 0; rg < 4; rg++) {
                int grow = mb + wm + i * 16 + quad * 4 + rg;
                int gcol = nb + wn + j * 16 + r;
                G[grow * N4 + gcol] = f2bf(acc[i][j][rg]);
            }
}

// ---------------------------------------------------------------------------
// Kernel 3: LSTM elementwise epilogue.
// gates[b][g*2048+j] + bias -> f,i,c~,o -> c_t, h_t (fp32 out).
// d_out = [h_t (B*H) | c_t (B*H)]
// ---------------------------------------------------------------------------
__global__ void lstm_epilogue(const u16* __restrict__ G,
                              const float* __restrict__ c_prev,
                              const float* __restrict__ bf_, const float* __restrict__ bi_,
                              const float* __restrict__ bc_, const float* __restrict__ bo_,
                              float* __restrict__ out) {
    int t = blockIdx.x * blockDim.x + threadIdx.x;   // 0 .. B*H-1 (8.4M, int ok)
    int j = t & 2047;
    int row = t >> 11;
    const u16* g = G + (long long)row * N4 + j;
    float gf = bf2f(g[0])    + bf_[j];
    float gi = bf2f(g[2048]) + bi_[j];
    float gc = bf2f(g[4096]) + bc_[j];
    float go = bf2f(g[6144]) + bo_[j];
    float f  = 1.f / (1.f + __expf(-gf));
    float ii = 1.f / (1.f + __expf(-gi));
    float ct = tanhf(gc);
    float oo = 1.f / (1.f + __expf(-go));
    float c  = f * c_prev[t] + ii * ct;
    float h  = oo * tanhf(c);
    out[t] = h;
    out[B_DIM * H_DIM + t] = c;
}

// ---------------------------------------------------------------------------
// Fallback (only if ws_size < 160 MiB): naive fp32, correct but slow.
// ---------------------------------------------------------------------------
__global__ void lstm_naive(const float* __restrict__ x_t, const float* __restrict__ h_prev,
                           const float* __restrict__ c_prev,
                           const float* __restrict__ Wf, const float* __restrict__ bf_,
                           const float* __restrict__ Wi, const float* __restrict__ bi_,
                           const float* __restrict__ Wc, const float* __restrict__ bc_,
                           const float* __restrict__ Wo, const float* __restrict__ bo_,
                           float* __restrict__ out) {
    int j = blockIdx.x * blockDim.x + threadIdx.x;  // 0..2047
    int b = blockIdx.y;                             // 0..4095
    const float* hrow = h_prev + (long long)b * H_DIM;
    const float* xrow = x_t   + (long long)b * I_DIM;
    const float* wf = Wf + (long long)j * K_DIM;
    const float* wi = Wi + (long long)j * K_DIM;
    const float* wc = Wc + (long long)j * K_DIM;
    const float* wo = Wo + (long long)j * K_DIM;
    float af = bf_[j], ai = bi_[j], ac = bc_[j], ao = bo_[j];
    for (int k = 0; k < H_DIM; k += 4) {
        float4 v = *(const float4*)(hrow + k);
        float4 a = *(const float4*)(wf + k);
        float4 bqi = *(const float4*)(wi + k);
        float4 cq = *(const float4*)(wc + k);
        float4 dq = *(const float4*)(wo + k);
        af += v.x*a.x + v.y*a.y + v.z*a.z + v.w*a.w;
        ai += v.x*bqi.x + v.y*bqi.y + v.z*bqi.z + v.w*bqi.w;
        ac += v.x*cq.x + v.y*cq.y + v.z*cq.z + v.w*cq.w;
        ao += v.x*dq.x + v.y*dq.y + v.z*dq.z + v.w*dq.w;
    }
    for (int k = 0; k < I_DIM; k += 4) {
        float4 v = *(const float4*)(xrow + k);
        float4 a = *(const float4*)(wf + H_DIM + k);
        float4 bqi = *(const float4*)(wi + H_DIM + k);
        float4 cq = *(const float4*)(wc + H_DIM + k);
        float4 dq = *(const float4*)(wo + H_DIM + k);
        af += v.x*a.x + v.y*a.y + v.z*a.z + v.w*a.w;
        ai += v.x*bqi.x + v.y*bqi.y + v.z*bqi.z + v.w*bqi.w;
        ac += v.x*cq.x + v.y*cq.y + v.z*cq.z + v.w*cq.w;
        ao += v.x*dq.x + v.y*dq.y + v.z*dq.z + v.w*dq.w;
    }
    float f  = 1.f / (1.f + __expf(-af));
    float ii = 1.f / (1.f + __expf(-ai));
    float ct = tanhf(ac);
    float oo = 1.f / (1.f + __expf(-ao));
    int t = b * H_DIM + j;
    float c = f * c_prev[t] + ii * ct;
    out[t] = oo * tanhf(c);
    out[B_DIM * H_DIM + t] = c;
}

extern "C" void kernel_launch(void* const* d_in, const int* in_sizes, int n_in,
                              void* d_out, int out_size, void* d_ws, size_t ws_size,
                              hipStream_t stream) {
    const float* x_t    = (const float*)d_in[0];
    const float* h_prev = (const float*)d_in[1];
    const float* c_prev = (const float*)d_in[2];
    const float* Wf = (const float*)d_in[3];  const float* bf_ = (const float*)d_in[4];
    const float* Wi = (const float*)d_in[5];  const float* bi_ = (const float*)d_in[6];
    const float* Wc = (const float*)d_in[7];  const float* bc_ = (const float*)d_in[8];
    const float* Wo = (const float*)d_in[9];  const float* bo_ = (const float*)d_in[10];
    float* out = (float*)d_out;

    const size_t comb_elems  = (size_t)B_DIM * K_DIM;   // 16.7M u16
    const size_t wb_elems    = (size_t)N4 * K_DIM;      // 33.5M u16
    const size_t gates_elems = (size_t)B_DIM * N4;      // 33.5M u16
    const size_t need = (comb_elems + wb_elems + gates_elems) * sizeof(u16); // 160 MiB

    if (ws_size >= need) {
        u16* comb  = (u16*)d_ws;
        u16* wb    = comb + comb_elems;
        u16* gates = wb + wb_elems;
        convert_combined<<<(int)(comb_elems / 4 / 256), 256, 0, stream>>>(h_prev, x_t, comb);
        convert_w<<<(int)(wb_elems / 4 / 256), 256, 0, stream>>>(Wf, Wi, Wc, Wo, wb);
        dim3 grid(N4 / 128, B_DIM / 128);  // (64, 32)
        gemm_gates<<<grid, 256, 0, stream>>>(comb, wb, gates);
        lstm_epilogue<<<(int)((size_t)B_DIM * H_DIM / 256), 256, 0, stream>>>(
            gates, c_prev, bf_, bi_, bc_, bo_, out);
    } else {
        dim3 grid(H_DIM / 256, B_DIM);
        lstm_naive<<<grid, 256, 0, stream>>>(x_t, h_prev, c_prev,
                                             Wf, bf_, Wi, bi_, Wc, bc_, Wo, bo_, out);
    }
}